// Round 12
// baseline (393.270 us; speedup 1.0000x reference)
//
#include <hip/hip_runtime.h>
#include <hip/hip_bf16.h>

#define N_ 8192
#define I_ 1024
#define O_ 1024
#define P_ 8
#define C_ 64
#define OP_ (O_ * P_)

typedef float f32x4 __attribute__((ext_vector_type(4)));
typedef __bf16 bf16x8 __attribute__((ext_vector_type(8)));
typedef unsigned short ushort8 __attribute__((ext_vector_type(8)));

#define GLOBAL_AS(p) ((const __attribute__((address_space(1))) unsigned int*)(p))
#define LDS_AS(p) ((__attribute__((address_space(3))) unsigned int*)(p))

// Tiled operand layout: 20 K-tiles per 256-row block (rb).
//   tiles 0..15 : main GEMM K=1024 (X rows / W rows), bf16
//   tiles 16..19: cross K=64 each: A-side {ch,ch,cl,cl}, B-side {ph,pl,ph,pl}
//     (ch+cl)(ph+pl) summed over 4 tiles = full-precision cross <protos,ctx>
// chunk index within rb: kt*2048 + h*1024 + L  (L = Lr*8 + j, c = j^(Lr&7))
// rb stride = 40960 chunks = 327680 ushorts.

// ---------------------------------------------------------------------------
// Kernel P: all data prep in one launch.
//  b in [0,8192): main converts (X->Xb / W->Wb), validated mapping (r7-r11)
//  b in [8192,10240): cross tiles (ctx->Xb[16..19], protos->Wb[16..19]) hi/lo
//  b in [10240,10272): psq[o*8+p] = sum_c protos^2 (fp32 exact)
// ---------------------------------------------------------------------------
__global__ __launch_bounds__(256)
void prepare_all_kernel(const float* __restrict__ X, const float* __restrict__ W,
                        const float* __restrict__ ctx, const float* __restrict__ protos,
                        unsigned short* __restrict__ Xb, unsigned short* __restrict__ Wb,
                        float* __restrict__ psq) {
    const int b = blockIdx.x;
    const int tid = threadIdx.x;
    if (b < 8192) {
        const int side = b >> 12;                    // 0: X (layout A), 1: W (layout B)
        const float* src = side ? W : X;
        unsigned short* dst = side ? Wb : Xb;
        const int idx = (b & 4095) * 256 + tid;      // 1,048,576 chunks
        const int rb = idx >> 15;
        const int r = idx & 32767;
        const int kt = r >> 11;
        const int h = (r >> 10) & 1;
        const int L = r & 1023;
        const int Lr = L >> 3;
        const int j = L & 7;
        const int c = j ^ (Lr & 7);
        int Rl;
        if (side == 0) Rl = (Lr & 63) + ((Lr & 64) << 1) + h * 64;
        else           Rl = ((Lr >> 5) << 6) + h * 32 + (Lr & 31);
        const float* sp = src + (size_t)(rb * 256 + Rl) * I_ + kt * 64 + c * 8;
        const float4 f0 = *(const float4*)(sp);
        const float4 f1 = *(const float4*)(sp + 4);
        const float f[8] = {f0.x, f0.y, f0.z, f0.w, f1.x, f1.y, f1.z, f1.w};
        ushort8 v;
        #pragma unroll
        for (int e = 0; e < 8; ++e)
            v[e] = __builtin_bit_cast(unsigned short, __float2bfloat16(f[e]));
        *(ushort8*)(dst + ((size_t)rb * 40960 + r) * 8) = v;
    } else if (b < 10240) {
        const int side = (b - 8192) >> 10;           // 0: ctx->Xb, 1: protos->Wb
        const int idx = ((b - 8192) & 1023) * 256 + tid;  // 262,144 chunks/side
        const int rb = idx >> 13;
        const int r2 = idx & 8191;
        const int kt2 = r2 >> 11;                    // 0..3
        const int h = (r2 >> 10) & 1;
        const int L = r2 & 1023;
        const int Lr = L >> 3;
        const int j = L & 7;
        const int c = j ^ (Lr & 7);
        int Rl;
        if (side == 0) Rl = (Lr & 63) + ((Lr & 64) << 1) + h * 64;
        else           Rl = ((Lr >> 5) << 6) + h * 32 + (Lr & 31);
        const float* sp = (side ? protos : ctx) + (size_t)(rb * 256 + Rl) * C_ + c * 8;
        const bool hi = side ? ((kt2 & 1) == 0) : (kt2 < 2);
        const float4 f0 = *(const float4*)(sp);
        const float4 f1 = *(const float4*)(sp + 4);
        const float f[8] = {f0.x, f0.y, f0.z, f0.w, f1.x, f1.y, f1.z, f1.w};
        ushort8 v;
        #pragma unroll
        for (int e = 0; e < 8; ++e) {
            const __hip_bfloat16 hh = __float2bfloat16(f[e]);
            v[e] = hi ? __builtin_bit_cast(unsigned short, hh)
                      : __builtin_bit_cast(unsigned short, __float2bfloat16(f[e] - __bfloat162float(hh)));
        }
        unsigned short* dst = side ? Wb : Xb;
        *(ushort8*)(dst + ((size_t)rb * 40960 + (size_t)(16 + kt2) * 2048 + h * 1024 + L) * 8) = v;
    } else {
        const int idx = (b - 10240) * 256 + tid;     // 0..8191
        const float* pr = protos + (size_t)idx * C_;
        float s = 0.f;
        #pragma unroll
        for (int c = 0; c < C_; ++c) s = fmaf(pr[c], pr[c], s);
        psq[idx] = s;
    }
}

// ---------------------------------------------------------------------------
// Exact fp64 argmin of the lane's 4 prototypes + partner merge (xor 16).
// Reproduces refine_wl semantics (validated r9-r11): ascending-p first-min.
// ---------------------------------------------------------------------------
__device__ __attribute__((noinline))
int refine8(const float* __restrict__ ctx, const float* __restrict__ protos,
            int opc0, int n, int lkbit) {
    const float* cr = ctx + (size_t)n * C_;
    double m1 = 1e300;
    int i1 = 0;
    #pragma unroll 1
    for (int j = 0; j < 4; ++j) {
        const float* pr = protos + (size_t)(opc0 + j) * C_;
        double s = 0.0;
        #pragma unroll
        for (int c4 = 0; c4 < 16; ++c4) {
            const float4 p4 = *(const float4*)(pr + c4 * 4);
            const float4 c4v = *(const float4*)(cr + c4 * 4);
            s += (double)p4.x * ((double)p4.x - 2.0 * (double)c4v.x);
            s += (double)p4.y * ((double)p4.y - 2.0 * (double)c4v.y);
            s += (double)p4.z * ((double)p4.z - 2.0 * (double)c4v.z);
            s += (double)p4.w * ((double)p4.w - 2.0 * (double)c4v.w);
        }
        const int p = lkbit * 4 + j;
        if (s < m1) { m1 = s; i1 = p; }
    }
    const double m2 = __shfl_xor(m1, 16, 64);
    const int i2 = __shfl_xor(i1, 16, 64);
    if (m2 < m1 || (m2 == m1 && i2 < i1)) i1 = i2;
    return i1;
}

// ---------------------------------------------------------------------------
// Kernel B: fully-fused 256x256 bf16 MFMA GEMM + in-register argmin + gather.
// Phase I (tiles 16..19): cross = <protos,ctx> with SWAPPED mfma operands
//   (D rows = opcol) so each o's 8 p-values sit in a lane pair (xor 16) —
//   argmin via the validated 1-shfl reduce; near-ties (margin<4e-3) get the
//   exact fp64 refine in-place. Result packed 3b/entry into pk[4].
// Phase II (tiles 0..15): r10's validated schedule (151us) verbatim.
// Epilogue: ds_bpermute redistributes packed p; gather + bias as before.
// ---------------------------------------------------------------------------
__global__ __launch_bounds__(512, 1)
void gemm_fused_kernel(const unsigned short* __restrict__ Xb,
                       const unsigned short* __restrict__ Wb,
                       const float* __restrict__ bias,
                       const float* __restrict__ psq,
                       const float* __restrict__ ctx,
                       const float* __restrict__ protos,
                       float* __restrict__ out) {
    extern __shared__ unsigned short lds[];  // 2 bufs x (A 32KB + B 32KB) = 128 KiB

    int wg = blockIdx.x;                     // 1024 blocks, %8==0 -> bijective
    wg = (wg & 7) * 128 + (wg >> 3);
    const int bx = wg & 31;
    const int by = wg >> 5;
    const int n0 = by * 256;
    const int col0 = bx * 256;

    const int tid = threadIdx.x;
    const int w = tid >> 6, l = tid & 63;
    const int wr = w >> 2, wc = w & 3;
    const int lr = l & 15, lk = l >> 4;
    const int lx = lr & 7;

    const unsigned short* Xrb = Xb + (size_t)(n0 >> 8) * 327680;
    const unsigned short* Wrb = Wb + (size_t)(col0 >> 8) * 327680;

    #define STAGE(src, ktt, h, ldsofs) do {                                          \
        const unsigned short* _g = (src) + ((size_t)(ktt) * 2 + (h)) * 8192;         \
        __builtin_amdgcn_global_load_lds(GLOBAL_AS(_g + (size_t)tid * 8),            \
            LDS_AS(lds + (ldsofs) + tid * 8), 16, 0, 0);                             \
        __builtin_amdgcn_global_load_lds(GLOBAL_AS(_g + (size_t)(tid + 512) * 8),    \
            LDS_AS(lds + (ldsofs) + (tid + 512) * 8), 16, 0, 0);                     \
    } while (0)

    #define VMCNT4() do { asm volatile("s_waitcnt vmcnt(4)" ::: "memory");           \
        __builtin_amdgcn_sched_barrier(0); } while (0)
    #define VMCNT2() do { asm volatile("s_waitcnt vmcnt(2)" ::: "memory");           \
        __builtin_amdgcn_sched_barrier(0); } while (0)
    #define VMCNT0() do { asm volatile("s_waitcnt vmcnt(0)" ::: "memory");           \
        __builtin_amdgcn_sched_barrier(0); } while (0)
    #define LGKM0() do { asm volatile("s_waitcnt lgkmcnt(0)" ::: "memory");          \
        __builtin_amdgcn_sched_barrier(0); } while (0)
    #define BAR() __builtin_amdgcn_s_barrier()

    f32x4 acc[8][4];
    #pragma unroll
    for (int m = 0; m < 8; ++m)
        #pragma unroll
        for (int n = 0; n < 4; ++n) acc[m][n] = (f32x4)(0.f);
    unsigned pk[4] = {0u, 0u, 0u, 0u};

    // A-region row map (layout 0) / B-region row map (layout 1), validated r7+
    #define RD_A(dst, mbase, bb) do {                                                \
        _Pragma("unroll")                                                            \
        for (int _m = 0; _m < 4; ++_m) {                                             \
            const int _R = wr * 128 + ((mbase) + _m) * 16 + lr;                      \
            const int _h = (_R >> 6) & 1;                                            \
            const int _Lr = (_R & 63) + ((_R & 128) >> 1);                           \
            _Pragma("unroll")                                                        \
            for (int _k = 0; _k < 2; ++_k) {                                         \
                const int _s = (_k * 4 + lk) ^ lx;                                   \
                dst[_m][_k] = *(const bf16x8*)&lds[(bb) * 32768 + _h * 8192 +        \
                                                   _Lr * 64 + _s * 8];               \
            }                                                                        \
        }                                                                            \
    } while (0)

    #define RD_B(dst, nbase, bb) do {                                                \
        _Pragma("unroll")                                                            \
        for (int _n = 0; _n < 2; ++_n) {                                             \
            const int _R = wc * 64 + ((nbase) + _n) * 16 + lr;                       \
            const int _h = (_R >> 5) & 1;                                            \
            const int _Lr = ((_R >> 6) << 5) + (_R & 31);                            \
            _Pragma("unroll")                                                        \
            for (int _k = 0; _k < 2; ++_k) {                                         \
                const int _s = (_k * 4 + lk) ^ lx;                                   \
                dst[_n][_k] = *(const bf16x8*)&lds[(bb) * 32768 + 16384 +            \
                                                   _h * 8192 + _Lr * 64 + _s * 8];   \
            }                                                                        \
        }                                                                            \
    } while (0)

    // Phase-I reads: all 4 proto frags (B-region), 2-frag ctx window (A-region)
    #define RD_P(bb) do {                                                            \
        _Pragma("unroll")                                                            \
        for (int _p = 0; _p < 4; ++_p) {                                             \
            const int _R = wc * 64 + _p * 16 + lr;                                   \
            const int _h = (_R >> 5) & 1;                                            \
            const int _Lr = ((_R >> 6) << 5) + (_R & 31);                            \
            _Pragma("unroll")                                                        \
            for (int _k = 0; _k < 2; ++_k) {                                         \
                const int _s = (_k * 4 + lk) ^ lx;                                   \
                pf[_p][_k] = *(const bf16x8*)&lds[(bb) * 32768 + 16384 +             \
                                                  _h * 8192 + _Lr * 64 + _s * 8];    \
            }                                                                        \
        }                                                                            \
    } while (0)

    #define RD_C(nnbase, bb) do {                                                    \
        _Pragma("unroll")                                                            \
        for (int _i = 0; _i < 2; ++_i) {                                             \
            const int _R = wr * 128 + ((nnbase) + _i) * 16 + lr;                     \
            const int _h = (_R >> 6) & 1;                                            \
            const int _Lr = (_R & 63) + ((_R & 128) >> 1);                           \
            _Pragma("unroll")                                                        \
            for (int _k = 0; _k < 2; ++_k) {                                         \
                const int _s = (_k * 4 + lk) ^ lx;                                   \
                cf[_i][_k] = *(const bf16x8*)&lds[(bb) * 32768 + _h * 8192 +         \
                                                  _Lr * 64 + _s * 8];                \
            }                                                                        \
        }                                                                            \
    } while (0)

    #define MFMA16(AF, BF, MB, NB) do {                                              \
        __builtin_amdgcn_s_setprio(1);                                               \
        _Pragma("unroll")                                                            \
        for (int _m = 0; _m < 4; ++_m)                                               \
            _Pragma("unroll")                                                        \
            for (int _n = 0; _n < 2; ++_n)                                           \
                _Pragma("unroll")                                                    \
                for (int _k = 0; _k < 2; ++_k)                                       \
                    acc[(MB) + _m][(NB) + _n] =                                      \
                        __builtin_amdgcn_mfma_f32_16x16x32_bf16(                     \
                            AF[_m][_k], BF[_n][_k], acc[(MB) + _m][(NB) + _n], 0, 0, 0); \
        __builtin_amdgcn_s_setprio(0);                                               \
    } while (0)

    // transposed: D = mfma(proto, ctx) -> rows = opcol, cols = n
    #define MFMA16T(NNB) do {                                                        \
        __builtin_amdgcn_s_setprio(1);                                               \
        _Pragma("unroll")                                                            \
        for (int _i = 0; _i < 2; ++_i)                                               \
            _Pragma("unroll")                                                        \
            for (int _p = 0; _p < 4; ++_p)                                           \
                _Pragma("unroll")                                                    \
                for (int _k = 0; _k < 2; ++_k)                                       \
                    acc[(NNB) + _i][_p] =                                            \
                        __builtin_amdgcn_mfma_f32_16x16x32_bf16(                     \
                            pf[_p][_k], cf[_i][_k], acc[(NNB) + _i][_p], 0, 0, 0);   \
        __builtin_amdgcn_s_setprio(0);                                               \
    } while (0)

    bf16x8 pf[4][2], cf[2][2];
    bf16x8 af[4][2], bfa[2][2], bfb[2][2];

    // ---- prologue: stage cross tile 16 into buf0 (Aa,Ba,Bb,Ab) ----
    STAGE(Xrb, 16, 0, 0);
    STAGE(Wrb, 16, 0, 16384);
    STAGE(Wrb, 16, 1, 16384 + 8192);
    STAGE(Xrb, 16, 1, 8192);
    VMCNT2();                         // completes Aa,Ba,Bb (P1 reads all three)
    BAR();

    // ---- Phase I: cross tiles 16..19; stage order {Ba',Aa',Bb',Ab'};
    //      waits only at P2 (vmcnt2 -> Ab of current) and P4 (vmcnt2 ->
    //      Ba',Aa',Bb' of next). Derived race-free by queue simulation.
    #define CROSS_TILE(bb, SN) do {                                                  \
        const int _nbo = ((bb) ^ 1) * 32768;                                         \
        RD_P(bb); RD_C(0, bb);                                                       \
        STAGE(Wrb, SN, 0, _nbo + 16384);                                             \
        BAR(); LGKM0(); MFMA16T(0);                                                  \
        RD_C(2, bb);                                                                 \
        STAGE(Xrb, SN, 0, _nbo);                                                     \
        VMCNT2(); BAR(); LGKM0(); MFMA16T(2);                                        \
        RD_C(4, bb);                                                                 \
        STAGE(Wrb, SN, 1, _nbo + 16384 + 8192);                                      \
        BAR(); LGKM0(); MFMA16T(4);                                                  \
        RD_C(6, bb);                                                                 \
        STAGE(Xrb, SN, 1, _nbo + 8192);                                              \
        VMCNT2(); BAR(); LGKM0(); MFMA16T(6);                                        \
    } while (0)

    CROSS_TILE(0, 17);
    CROSS_TILE(1, 18);
    CROSS_TILE(0, 19);
    CROSS_TILE(1, 0);   // stages main tile 0 into buf0

    // ---- interlude: per-(n,o) argmin from cross acc; pack 3b/entry ----
    {
        #pragma unroll
        for (int po = 0; po < 4; ++po) {
            const int opc0 = col0 + wc * 64 + po * 16 + lk * 4;  // lane's j=0 opcol
            const f32x4 ps = *(const f32x4*)(psq + opc0);
            #pragma unroll
            for (int nn = 0; nn < 8; ++nn) {
                const int n = n0 + wr * 128 + nn * 16 + lr;
                float d[4], e[4];
                #pragma unroll
                for (int j = 0; j < 4; ++j) {
                    d[j] = fmaf(-2.f, acc[nn][po][j], ps[j]);
                    e[j] = __shfl_xor(d[j], 16, 64);
                }
                float b1v = 3.4e38f, b2v = 3.4e38f;
                int bi = 0;
                #pragma unroll
                for (int p = 0; p < 8; ++p) {
                    const float f = ((p >> 2) == (lk & 1)) ? d[p & 3] : e[p & 3];
                    if (f < b1v) { b2v = b1v; b1v = f; bi = p; }
                    else if (f < b2v) b2v = f;
                }
                if (b2v - b1v < 4e-3f)
                    bi = refine8(ctx, protos, opc0, n, lk & 1);
                pk[po] |= (unsigned)bi << (nn * 4);
            }
        }
        // reset accumulators for the main GEMM
        #pragma unroll
        for (int m = 0; m < 8; ++m)
            #pragma unroll
            for (int n = 0; n < 4; ++n) acc[m][n] = (f32x4)(0.f);
    }

    // ---- Phase II: main tiles 0..15, r10 schedule verbatim (151us) ----
    #pragma unroll 1
    for (int kt = 0; kt < 15; ++kt) {
        const int b = kt & 1, nb = b ^ 1;
        const int nbo = nb * 32768;
        RD_A(af, 0, b);
        RD_B(bfa, 0, b);
        STAGE(Wrb, kt + 1, 0, nbo + 16384);
        VMCNT4(); BAR(); LGKM0();
        MFMA16(af, bfa, 0, 0);
        RD_B(bfb, 2, b);
        STAGE(Xrb, kt + 1, 0, nbo);
        VMCNT4(); BAR(); LGKM0();
        MFMA16(af, bfb, 0, 2);
        RD_A(af, 4, b);
        STAGE(Wrb, kt + 1, 1, nbo + 16384 + 8192);
        VMCNT4(); BAR(); LGKM0();
        MFMA16(af, bfb, 4, 2);
        RD_B(bfa, 0, b);
        STAGE(Xrb, kt + 1, 1, nbo + 8192);
        VMCNT4(); BAR(); LGKM0();
        MFMA16(af, bfa, 4, 0);
    }
    {   // tail kt=15 (buf 1, no staging)
        RD_A(af, 0, 1);
        RD_B(bfa, 0, 1);
        VMCNT2(); BAR(); LGKM0();
        MFMA16(af, bfa, 0, 0);
        RD_B(bfb, 2, 1);
        VMCNT0(); BAR(); LGKM0();
        MFMA16(af, bfb, 0, 2);
        RD_A(af, 4, 1);
        LGKM0();
        MFMA16(af, bfb, 4, 2);
        RD_B(bfa, 0, 1);
        LGKM0();
        MFMA16(af, bfa, 4, 0);
    }

    // ---- epilogue: bpermute packed argmin; gather + bias ----
    const int nbase = n0 + wr * 128 + lk * 4;
    #pragma unroll
    for (int nf = 0; nf < 4; ++nf) {
        const int opcol = col0 + wc * 64 + nf * 16 + lr;
        const int o = opcol >> 3;
        const unsigned myp = (unsigned)(opcol & 7);
        const float bv = bias[opcol];
        #pragma unroll
        for (int j = 0; j < 4; ++j) {
            const int srcl = ((lr >> 3) << 5) + lk * 4 + j;
            const unsigned pulled = (unsigned)__builtin_amdgcn_ds_bpermute(srcl << 2, (int)pk[nf]);
            #pragma unroll
            for (int m = 0; m < 8; ++m) {
                if (((pulled >> (m * 4)) & 7u) == myp) {
                    const int n = nbase + m * 16 + j;
                    out[(size_t)n * O_ + o] = acc[m][nf][j] + bv;
                }
            }
        }
    }
    #undef STAGE
    #undef RD_A
    #undef RD_B
    #undef RD_P
    #undef RD_C
    #undef MFMA16
    #undef MFMA16T
    #undef CROSS_TILE
    #undef VMCNT4
    #undef VMCNT2
    #undef VMCNT0
    #undef LGKM0
    #undef BAR
}

// ---------------------------------------------------------------------------
extern "C" void kernel_launch(void* const* d_in, const int* in_sizes, int n_in,
                              void* d_out, int out_size, void* d_ws, size_t ws_size,
                              hipStream_t stream) {
    const float* X      = (const float*)d_in[0];
    const float* ctx    = (const float*)d_in[1];
    const float* W      = (const float*)d_in[2];
    const float* bias   = (const float*)d_in[3];
    const float* protos = (const float*)d_in[4];
    float* out = (float*)d_out;

    char* ws = (char*)d_ws;
    float* psq = (float*)ws;                                          // 32 KiB
    unsigned short* Xb = (unsigned short*)(ws + ((size_t)1 << 20));   // 20 MiB
    unsigned short* Wb = (unsigned short*)(ws + ((size_t)21 << 20));  // 20 MiB

    hipFuncSetAttribute((const void*)gemm_fused_kernel,
                        hipFuncAttributeMaxDynamicSharedMemorySize, 131072);

    prepare_all_kernel<<<dim3(10272), dim3(256), 0, stream>>>(X, W, ctx, protos, Xb, Wb, psq);
    gemm_fused_kernel<<<dim3(1024), dim3(512), 131072, stream>>>(Xb, Wb, bias, psq, ctx, protos, out);
}

// Round 13
// 295.807 us; speedup vs baseline: 1.3295x; 1.3295x over previous
//
#include <hip/hip_runtime.h>
#include <hip/hip_bf16.h>

#define N_ 8192
#define I_ 1024
#define O_ 1024
#define P_ 8
#define C_ 64
#define OP_ (O_ * P_)

typedef float f32x4 __attribute__((ext_vector_type(4)));
typedef __bf16 bf16x8 __attribute__((ext_vector_type(8)));
typedef unsigned short ushort8 __attribute__((ext_vector_type(8)));

#define GLOBAL_AS(p) ((const __attribute__((address_space(1))) unsigned int*)(p))
#define LDS_AS(p) ((__attribute__((address_space(3))) unsigned int*)(p))

// ---------------------------------------------------------------------------
// Kernel P: fused prep. Blocks 0-255: split protos -> ph,pl. 256-511: split
// ctx -> ch,cl. 512-543: psq (fp32 exact, sequential-c order).
// ---------------------------------------------------------------------------
__global__ __launch_bounds__(256)
void prep_kernel(const float* __restrict__ protos, const float* __restrict__ ctx,
                 unsigned short* __restrict__ ph, unsigned short* __restrict__ pl,
                 unsigned short* __restrict__ ch, unsigned short* __restrict__ cl,
                 float* __restrict__ psq) {
    const int b = blockIdx.x;
    if (b < 512) {
        const float* src = (b < 256) ? protos : ctx;
        unsigned short* hi = (b < 256) ? ph : ch;
        unsigned short* lo = (b < 256) ? pl : cl;
        const int idx = (b & 255) * 256 + threadIdx.x;
        const float* sp = src + (size_t)idx * 8;
        const float4 f0 = *(const float4*)(sp);
        const float4 f1 = *(const float4*)(sp + 4);
        float f[8] = {f0.x, f0.y, f0.z, f0.w, f1.x, f1.y, f1.z, f1.w};
        ushort8 vh, vl;
        #pragma unroll
        for (int e = 0; e < 8; ++e) {
            const __hip_bfloat16 h = __float2bfloat16(f[e]);
            const __hip_bfloat16 l = __float2bfloat16(f[e] - __bfloat162float(h));
            vh[e] = __builtin_bit_cast(unsigned short, h);
            vl[e] = __builtin_bit_cast(unsigned short, l);
        }
        *(ushort8*)(hi + (size_t)idx * 8) = vh;
        *(ushort8*)(lo + (size_t)idx * 8) = vl;
    } else {
        const int idx = (b - 512) * 256 + threadIdx.x;  // 0..8191
        const float* pr = protos + (size_t)idx * C_;
        float s = 0.f;
        #pragma unroll
        for (int c = 0; c < C_; ++c) s = fmaf(pr[c], pr[c], s);
        psq[idx] = s;
    }
}

// ---------------------------------------------------------------------------
// Kernel M: MEGA — converts + argmin interleaved in one launch so BW-bound
// convert blocks and latency-bound argmin blocks co-schedule on CUs.
//   bid%3==2 -> argmin block (aidx = bid/3, 4096 total; r10-verbatim path,
//               flag threshold 4e-3 per the 3-term split error bound)
//   else     -> convert block (cidx = bid - (bid+1)/3, 8192 total;
//               r10-verbatim tiled-swizzled convert; side = cidx>>12)
// ---------------------------------------------------------------------------
__global__ __launch_bounds__(256, 2)
void mega_kernel(const float* __restrict__ X, const float* __restrict__ W,
                 unsigned short* __restrict__ Xb, unsigned short* __restrict__ Wb,
                 const unsigned short* __restrict__ ph, const unsigned short* __restrict__ pl,
                 const unsigned short* __restrict__ ch, const unsigned short* __restrict__ cl,
                 const float* __restrict__ psq, unsigned char* __restrict__ best) {
    const int bid = blockIdx.x;
    const int tid = threadIdx.x;

    if (bid % 3 != 2) {
        // ---------------- convert role (r10 convert_tiled verbatim) ----------
        const int cidx = bid - (bid + 1) / 3;        // 0..8191
        const int side = cidx >> 12;                 // 0: X (layout A), 1: W (layout B)
        const float* src = side ? W : X;
        unsigned short* dst = side ? Wb : Xb;
        const int idx = (cidx & 4095) * 256 + tid;   // 1,048,576 chunks
        const int rb = idx >> 15;
        const int r = idx & 32767;
        const int kt = r >> 11;
        const int h = (r >> 10) & 1;
        const int L = r & 1023;
        const int Lr = L >> 3;
        const int j = L & 7;
        const int c = j ^ (Lr & 7);
        int Rl;
        if (side == 0) Rl = (Lr & 63) + ((Lr & 64) << 1) + h * 64;
        else           Rl = ((Lr >> 5) << 6) + h * 32 + (Lr & 31);
        const float* sp = src + (size_t)(rb * 256 + Rl) * I_ + kt * 64 + c * 8;
        const float4 f0 = *(const float4*)(sp);
        const float4 f1 = *(const float4*)(sp + 4);
        const float f[8] = {f0.x, f0.y, f0.z, f0.w, f1.x, f1.y, f1.z, f1.w};
        ushort8 v;
        #pragma unroll
        for (int e = 0; e < 8; ++e)
            v[e] = __builtin_bit_cast(unsigned short, __float2bfloat16(f[e]));
        *(ushort8*)(dst + (size_t)idx * 8) = v;
        return;
    }

    // ---------------- argmin role (r10 argmin_mfma verbatim, thr 4e-3) ------
    const int aidx = bid / 3;                        // 0..4095
    const int w = tid >> 6, l = tid & 63;
    const int op0 = (aidx & 63) * 128;
    const int nw = (aidx >> 6) * 128 + w * 32;
    const int lr = l & 15, lk = l >> 4;

    f32x4 acc[8][2];
    #pragma unroll
    for (int of = 0; of < 8; ++of)
        #pragma unroll
        for (int nf = 0; nf < 2; ++nf) acc[of][nf] = (f32x4)(0.f);

    #pragma unroll
    for (int ks = 0; ks < 2; ++ks) {
        const int ko = ks * 32 + lk * 8;
        bf16x8 Ah[8], Al[8], Bh[2], Bl[2];
        #pragma unroll
        for (int of = 0; of < 8; ++of) {
            const size_t r = (size_t)(op0 + of * 16 + lr) * C_ + ko;
            Ah[of] = *(const bf16x8*)(ph + r);
            Al[of] = *(const bf16x8*)(pl + r);
        }
        #pragma unroll
        for (int nf = 0; nf < 2; ++nf) {
            const size_t r = (size_t)(nw + nf * 16 + lr) * C_ + ko;
            Bh[nf] = *(const bf16x8*)(ch + r);
            Bl[nf] = *(const bf16x8*)(cl + r);
        }
        #pragma unroll
        for (int of = 0; of < 8; ++of)
            #pragma unroll
            for (int nf = 0; nf < 2; ++nf) {
                acc[of][nf] = __builtin_amdgcn_mfma_f32_16x16x32_bf16(Ah[of], Bh[nf], acc[of][nf], 0, 0, 0);
                acc[of][nf] = __builtin_amdgcn_mfma_f32_16x16x32_bf16(Ah[of], Bl[nf], acc[of][nf], 0, 0, 0);
                acc[of][nf] = __builtin_amdgcn_mfma_f32_16x16x32_bf16(Al[of], Bh[nf], acc[of][nf], 0, 0, 0);
            }
    }

    #pragma unroll
    for (int of = 0; of < 8; ++of) {
        const int oprow0 = op0 + of * 16;
        const f32x4 ps = *(const f32x4*)(psq + oprow0 + lk * 4);
        #pragma unroll
        for (int nf = 0; nf < 2; ++nf) {
            const float d0 = fmaf(-2.f, acc[of][nf][0], ps[0]);
            const float d1 = fmaf(-2.f, acc[of][nf][1], ps[1]);
            const float d2 = fmaf(-2.f, acc[of][nf][2], ps[2]);
            const float d3 = fmaf(-2.f, acc[of][nf][3], ps[3]);
            const float e0 = __shfl_xor(d0, 16, 64);
            const float e1 = __shfl_xor(d1, 16, 64);
            const float e2 = __shfl_xor(d2, 16, 64);
            const float e3 = __shfl_xor(d3, 16, 64);
            float b1v = 3.4e38f, b2v = 3.4e38f;
            int bi = 0;
            #define UPD(val, pidx) do { const float _f = (val);                       \
                if (_f < b1v) { b2v = b1v; b1v = _f; bi = (pidx); }                   \
                else if (_f < b2v) b2v = _f; } while (0)
            UPD(d0, 0); UPD(d1, 1); UPD(d2, 2); UPD(d3, 3);
            UPD(e0, 4); UPD(e1, 5); UPD(e2, 6); UPD(e3, 7);
            #undef UPD
            if ((lk & 1) == 0) {
                const int o = (oprow0 >> 3) + (lk >> 1);
                const int n = nw + nf * 16 + lr;
                const unsigned flag = (b2v - b1v < 4e-3f) ? 0x80u : 0u;
                best[(size_t)o * N_ + n] = (unsigned char)((unsigned)bi | flag);
            }
        }
    }
}

// ---------------------------------------------------------------------------
// Kernel A1.5: hierarchical compaction (validated r10). One atomic/block.
// ---------------------------------------------------------------------------
__global__ __launch_bounds__(256)
void compact_kernel(const uint4* __restrict__ bw4, unsigned* __restrict__ wl,
                    unsigned* __restrict__ wl_cnt) {
    __shared__ unsigned wsum[4];
    const int tid = threadIdx.x;
    const int gidx = blockIdx.x * 256 + tid;
    const uint4 v0 = bw4[(size_t)gidx * 2];
    const uint4 v1 = bw4[(size_t)gidx * 2 + 1];
    const unsigned words[8] = {v0.x, v0.y, v0.z, v0.w, v1.x, v1.y, v1.z, v1.w};
    unsigned k = 0;
    #pragma unroll
    for (int i = 0; i < 8; ++i) k += (unsigned)__popc(words[i] & 0x80808080u);

    const int lane = tid & 63;
    const int wv = tid >> 6;
    unsigned s = k;
    #pragma unroll
    for (int d = 1; d < 64; d <<= 1) {
        const unsigned t = __shfl_up(s, d, 64);
        if (lane >= d) s += t;
    }
    if (lane == 63) wsum[wv] = s;
    __syncthreads();
    if (tid == 0) {
        const unsigned t0 = wsum[0], t1 = wsum[1], t2 = wsum[2], t3 = wsum[3];
        const unsigned tot = t0 + t1 + t2 + t3;
        const unsigned base = tot ? atomicAdd(wl_cnt, tot) : 0u;
        wsum[0] = base;
        wsum[1] = base + t0;
        wsum[2] = base + t0 + t1;
        wsum[3] = base + t0 + t1 + t2;
    }
    __syncthreads();
    unsigned my = wsum[wv] + s - k;
    if (k) {
        #pragma unroll
        for (int i = 0; i < 8; ++i) {
            const unsigned fl = words[i] & 0x80808080u;
            if (!fl) continue;
            #pragma unroll
            for (int bq = 0; bq < 4; ++bq) {
                if ((fl >> (8 * bq + 7)) & 1u)
                    wl[my++] = (unsigned)gidx * 32u + (unsigned)(i * 4 + bq);
            }
        }
    }
}

// ---------------------------------------------------------------------------
// Kernel A2: parallel exact fp64 refine (validated r9-r11).
// ---------------------------------------------------------------------------
__global__ __launch_bounds__(256)
void refine_wl_kernel(const float* __restrict__ ctx, const float* __restrict__ protos,
                      const unsigned* __restrict__ wl, const unsigned* __restrict__ wl_cnt,
                      unsigned char* __restrict__ best) {
    const unsigned cnt = *wl_cnt;
    const int lane8 = threadIdx.x & 7;
    const unsigned gid = (unsigned)(blockIdx.x * 256 + threadIdx.x) >> 3;
    const unsigned stride = (gridDim.x * 256) >> 3;
    for (unsigned i = gid; i < cnt; i += stride) {
        const unsigned off = wl[i];
        const int n = (int)(off & (N_ - 1));
        const int o = (int)(off >> 13);
        const float* cr = ctx + (size_t)n * C_;
        const float* pr = protos + ((size_t)o * 8 + lane8) * C_;
        double s = 0.0;
        #pragma unroll 8
        for (int c = 0; c < C_; ++c) {
            const double pv = (double)pr[c];
            const double cv = (double)cr[c];
            s += pv * (pv - 2.0 * cv);
        }
        int bi = lane8;
        #pragma unroll
        for (int d = 1; d < 8; d <<= 1) {
            const double s2 = __shfl_xor(s, d, 64);
            const int b2 = __shfl_xor(bi, d, 64);
            if (s2 < s || (s2 == s && b2 < bi)) { s = s2; bi = b2; }
        }
        if (lane8 == 0) best[off] = (unsigned char)bi;
    }
}

// ---------------------------------------------------------------------------
// Kernel B: 256x256 phase-pipelined bf16 MFMA GEMM — r10 VERBATIM (151us) +
// fused argmin-gather epilogue.
// ---------------------------------------------------------------------------
__global__ __launch_bounds__(512, 1)
void gemm_gather_kernel(const unsigned short* __restrict__ Xb,
                        const unsigned short* __restrict__ Wb,
                        const float* __restrict__ bias,
                        const unsigned char* __restrict__ best,
                        float* __restrict__ out) {
    extern __shared__ unsigned short lds[];  // 2 x (A 16384 + B 16384) ushort = 128 KiB

    int wg = blockIdx.x;                     // 1024 blocks, %8==0 -> bijective
    wg = (wg & 7) * 128 + (wg >> 3);
    const int bx = wg & 31;
    const int by = wg >> 5;
    const int n0 = by * 256;
    const int col0 = bx * 256;

    const int tid = threadIdx.x;
    const int w = tid >> 6, l = tid & 63;
    const int wr = w >> 2, wc = w & 3;
    const int lr = l & 15, lk = l >> 4;
    const int lx = lr & 7;

    const unsigned short* Xrb = Xb + (size_t)(n0 >> 8) * 262144;
    const unsigned short* Wrb = Wb + (size_t)(col0 >> 8) * 262144;

    #define STAGE(src, ktt, h, ldsofs) do {                                          \
        const unsigned short* _g = (src) + ((size_t)(ktt) * 2 + (h)) * 8192;         \
        __builtin_amdgcn_global_load_lds(GLOBAL_AS(_g + (size_t)tid * 8),            \
            LDS_AS(lds + (ldsofs) + tid * 8), 16, 0, 0);                             \
        __builtin_amdgcn_global_load_lds(GLOBAL_AS(_g + (size_t)(tid + 512) * 8),    \
            LDS_AS(lds + (ldsofs) + (tid + 512) * 8), 16, 0, 0);                     \
    } while (0)

    #define VMCNT4() do { asm volatile("s_waitcnt vmcnt(4)" ::: "memory");           \
        __builtin_amdgcn_sched_barrier(0); } while (0)
    #define VMCNT2() do { asm volatile("s_waitcnt vmcnt(2)" ::: "memory");           \
        __builtin_amdgcn_sched_barrier(0); } while (0)
    #define VMCNT0() do { asm volatile("s_waitcnt vmcnt(0)" ::: "memory");           \
        __builtin_amdgcn_sched_barrier(0); } while (0)
    #define LGKM0() do { asm volatile("s_waitcnt lgkmcnt(0)" ::: "memory");          \
        __builtin_amdgcn_sched_barrier(0); } while (0)
    #define BAR() __builtin_amdgcn_s_barrier()

    f32x4 acc[8][4];
    #pragma unroll
    for (int m = 0; m < 8; ++m)
        #pragma unroll
        for (int n = 0; n < 4; ++n) acc[m][n] = (f32x4)(0.f);

    #define RD_A(dst, mbase, bb) do {                                                \
        _Pragma("unroll")                                                            \
        for (int _m = 0; _m < 4; ++_m) {                                             \
            const int _R = wr * 128 + ((mbase) + _m) * 16 + lr;                      \
            const int _h = (_R >> 6) & 1;                                            \
            const int _Lr = (_R & 63) + ((_R & 128) >> 1);                           \
            _Pragma("unroll")                                                        \
            for (int _k = 0; _k < 2; ++_k) {                                         \
                const int _s = (_k * 4 + lk) ^ lx;                                   \
                dst[_m][_k] = *(const bf16x8*)&lds[(bb) * 32768 + _h * 8192 +        \
                                                   _Lr * 64 + _s * 8];               \
            }                                                                        \
        }                                                                            \
    } while (0)

    #define RD_B(dst, nbase, bb) do {                                                \
        _Pragma("unroll")                                                            \
        for (int _n = 0; _n < 2; ++_n) {                                             \
            const int _R = wc * 64 + ((nbase) + _n) * 16 + lr;                       \
            const int _h = (_R >> 5) & 1;                                            \
            const int _Lr = ((_R >> 6) << 5) + (_R & 31);                            \
            _Pragma("unroll")                                                        \
            for (int _k = 0; _k < 2; ++_k) {                                         \
                const int _s = (_k * 4 + lk) ^ lx;                                   \
                dst[_n][_k] = *(const bf16x8*)&lds[(bb) * 32768 + 16384 +            \
                                                   _h * 8192 + _Lr * 64 + _s * 8];   \
            }                                                                        \
        }                                                                            \
    } while (0)

    #define MFMA16(AF, BF, MB, NB) do {                                              \
        __builtin_amdgcn_s_setprio(1);                                               \
        _Pragma("unroll")                                                            \
        for (int _m = 0; _m < 4; ++_m)                                               \
            _Pragma("unroll")                                                        \
            for (int _n = 0; _n < 2; ++_n)                                           \
                _Pragma("unroll")                                                    \
                for (int _k = 0; _k < 2; ++_k)                                       \
                    acc[(MB) + _m][(NB) + _n] =                                      \
                        __builtin_amdgcn_mfma_f32_16x16x32_bf16(                     \
                            AF[_m][_k], BF[_n][_k], acc[(MB) + _m][(NB) + _n], 0, 0, 0); \
        __builtin_amdgcn_s_setprio(0);                                               \
    } while (0)

    bf16x8 af[4][2], bfa[2][2], bfb[2][2];

    // ---- prologue: stage kt0 {Aa,Ba,Bb,Ab}; drain Aa0,Ba0 ----
    STAGE(Xrb, 0, 0, 0);
    STAGE(Wrb, 0, 0, 16384);
    STAGE(Wrb, 0, 1, 16384 + 8192);
    STAGE(Xrb, 0, 1, 8192);
    VMCNT4();
    BAR();

    #pragma unroll 1
    for (int kt = 0; kt < 15; ++kt) {
        const int b = kt & 1, nb = b ^ 1;
        const int nbo = nb * 32768;
        RD_A(af, 0, b);
        RD_B(bfa, 0, b);
        STAGE(Wrb, kt + 1, 0, nbo + 16384);
        VMCNT4();
        BAR();
        LGKM0();
        MFMA16(af, bfa, 0, 0);
        RD_B(bfb, 2, b);
        STAGE(Xrb, kt + 1, 0, nbo);
        VMCNT4();
        BAR();
        LGKM0();
        MFMA16(af, bfb, 0, 2);
        RD_A(af, 4, b);
        STAGE(Wrb, kt + 1, 1, nbo + 16384 + 8192);
        VMCNT4();
        BAR();
        LGKM0();
        MFMA16(af, bfb, 4, 2);
        RD_B(bfa, 0, b);
        STAGE(Xrb, kt + 1, 1, nbo + 8192);
        VMCNT4();
        BAR();
        LGKM0();
        MFMA16(af, bfa, 4, 0);
    }
    {   // tail kt=15 (buf 1, no staging)
        RD_A(af, 0, 1);
        RD_B(bfa, 0, 1);
        VMCNT2();
        BAR();
        LGKM0();
        MFMA16(af, bfa, 0, 0);
        RD_B(bfb, 2, 1);
        VMCNT0();
        BAR();
        LGKM0();
        MFMA16(af, bfb, 0, 2);
        RD_A(af, 4, 1);
        LGKM0();
        MFMA16(af, bfb, 4, 2);
        RD_B(bfa, 0, 1);
        LGKM0();
        MFMA16(af, bfa, 4, 0);
    }

    // ---- epilogue: fused argmin-gather + bias; u32 best loads ----
    const int nbase = n0 + wr * 128 + lk * 4;
    #pragma unroll
    for (int nf = 0; nf < 4; ++nf) {
        const int opcol = col0 + wc * 64 + nf * 16 + lr;
        const int o = opcol >> 3;
        const unsigned p = (unsigned)(opcol & 7);
        const float bv = bias[opcol];
        const unsigned char* brow = best + (size_t)o * N_ + nbase;
        #pragma unroll
        for (int m = 0; m < 8; ++m) {
            const unsigned b4 = *(const unsigned*)(brow + m * 16);
            #pragma unroll
            for (int j = 0; j < 4; ++j) {
                if (((b4 >> (j * 8)) & 255u) == p) {
                    const int n = nbase + m * 16 + j;
                    out[(size_t)n * O_ + o] = acc[m][nf][j] + bv;
                }
            }
        }
    }
    #undef STAGE
    #undef RD_A
    #undef RD_B
    #undef MFMA16
    #undef VMCNT4
    #undef VMCNT2
    #undef VMCNT0
    #undef LGKM0
    #undef BAR
}

// ---------------------------------------------------------------------------
extern "C" void kernel_launch(void* const* d_in, const int* in_sizes, int n_in,
                              void* d_out, int out_size, void* d_ws, size_t ws_size,
                              hipStream_t stream) {
    const float* X      = (const float*)d_in[0];
    const float* ctx    = (const float*)d_in[1];
    const float* W      = (const float*)d_in[2];
    const float* bias   = (const float*)d_in[3];
    const float* protos = (const float*)d_in[4];
    float* out = (float*)d_out;

    char* ws = (char*)d_ws;
    unsigned char* best = (unsigned char*)ws;                         // 8 MiB
    float* psq = (float*)(ws + ((size_t)8 << 20));                    // 32 KiB
    unsigned short* Xb = (unsigned short*)(ws + ((size_t)9 << 20));   // 16 MiB
    unsigned short* Wb = (unsigned short*)(ws + ((size_t)25 << 20));  // 16 MiB
    unsigned* wl_cnt = (unsigned*)(ws + ((size_t)41 << 20));          // 4 B

    // scratch in d_out (fully overwritten by gemm later)
    char* ob = (char*)d_out;
    unsigned short* ph = (unsigned short*)(ob + ((size_t)16 << 20));  // 1 MiB
    unsigned short* pl = (unsigned short*)(ob + ((size_t)17 << 20));  // 1 MiB
    unsigned short* ch = (unsigned short*)(ob + ((size_t)18 << 20));  // 1 MiB
    unsigned short* cl = (unsigned short*)(ob + ((size_t)19 << 20));  // 1 MiB
    unsigned* wl = (unsigned*)(ob + ((size_t)20 << 20));              // 8 MiB (2M entries)

    hipFuncSetAttribute((const void*)gemm_gather_kernel,
                        hipFuncAttributeMaxDynamicSharedMemorySize, 131072);

    hipMemsetAsync(wl_cnt, 0, 4, stream);
    prep_kernel<<<dim3(544), dim3(256), 0, stream>>>(protos, ctx, ph, pl, ch, cl, psq);
    mega_kernel<<<dim3(12288), dim3(256), 0, stream>>>(X, W, Xb, Wb, ph, pl, ch, cl, psq, best);
    compact_kernel<<<dim3(1024), dim3(256), 0, stream>>>((const uint4*)best, wl, wl_cnt);
    refine_wl_kernel<<<dim3(1024), dim3(256), 0, stream>>>(ctx, protos, wl, wl_cnt, best);
    gemm_gather_kernel<<<dim3(1024), dim3(512), 131072, stream>>>(Xb, Wb, bias, best, out);
}

// Round 14
// 276.924 us; speedup vs baseline: 1.4201x; 1.0682x over previous
//
#include <hip/hip_runtime.h>
#include <hip/hip_bf16.h>

#define N_ 8192
#define I_ 1024
#define O_ 1024
#define P_ 8
#define C_ 64
#define OP_ (O_ * P_)

typedef float f32x4 __attribute__((ext_vector_type(4)));
typedef __bf16 bf16x8 __attribute__((ext_vector_type(8)));
typedef unsigned short ushort8 __attribute__((ext_vector_type(8)));

#define GLOBAL_AS(p) ((const __attribute__((address_space(1))) unsigned int*)(p))
#define LDS_AS(p) ((__attribute__((address_space(3))) unsigned int*)(p))

// ---------------------------------------------------------------------------
// Kernel P: fused prep. Blocks 0-255: split protos -> ph,pl. 256-511: split
// ctx -> ch,cl. 512-543: psq (fp32 exact, sequential-c order).
// ---------------------------------------------------------------------------
__global__ __launch_bounds__(256)
void prep_kernel(const float* __restrict__ protos, const float* __restrict__ ctx,
                 unsigned short* __restrict__ ph, unsigned short* __restrict__ pl,
                 unsigned short* __restrict__ ch, unsigned short* __restrict__ cl,
                 float* __restrict__ psq) {
    const int b = blockIdx.x;
    if (b < 512) {
        const float* src = (b < 256) ? protos : ctx;
        unsigned short* hi = (b < 256) ? ph : ch;
        unsigned short* lo = (b < 256) ? pl : cl;
        const int idx = (b & 255) * 256 + threadIdx.x;
        const float* sp = src + (size_t)idx * 8;
        const float4 f0 = *(const float4*)(sp);
        const float4 f1 = *(const float4*)(sp + 4);
        float f[8] = {f0.x, f0.y, f0.z, f0.w, f1.x, f1.y, f1.z, f1.w};
        ushort8 vh, vl;
        #pragma unroll
        for (int e = 0; e < 8; ++e) {
            const __hip_bfloat16 h = __float2bfloat16(f[e]);
            const __hip_bfloat16 l = __float2bfloat16(f[e] - __bfloat162float(h));
            vh[e] = __builtin_bit_cast(unsigned short, h);
            vl[e] = __builtin_bit_cast(unsigned short, l);
        }
        *(ushort8*)(hi + (size_t)idx * 8) = vh;
        *(ushort8*)(lo + (size_t)idx * 8) = vl;
    } else {
        const int idx = (b - 512) * 256 + threadIdx.x;  // 0..8191
        const float* pr = protos + (size_t)idx * C_;
        float s = 0.f;
        #pragma unroll
        for (int c = 0; c < C_; ++c) s = fmaf(pr[c], pr[c], s);
        psq[idx] = s;
    }
}

// ---------------------------------------------------------------------------
// Kernel M: MEGA — converts + argmin interleaved (validated r13).
//   bid%3==2 -> argmin block (r10 path, flag thr 4e-3)
//   else     -> convert block (tiled-swizzled convert)
// ---------------------------------------------------------------------------
__global__ __launch_bounds__(256, 2)
void mega_kernel(const float* __restrict__ X, const float* __restrict__ W,
                 unsigned short* __restrict__ Xb, unsigned short* __restrict__ Wb,
                 const unsigned short* __restrict__ ph, const unsigned short* __restrict__ pl,
                 const unsigned short* __restrict__ ch, const unsigned short* __restrict__ cl,
                 const float* __restrict__ psq, unsigned char* __restrict__ best) {
    const int bid = blockIdx.x;
    const int tid = threadIdx.x;

    if (bid % 3 != 2) {
        // ---------------- convert role ----------------
        const int cidx = bid - (bid + 1) / 3;        // 0..8191
        const int side = cidx >> 12;
        const float* src = side ? W : X;
        unsigned short* dst = side ? Wb : Xb;
        const int idx = (cidx & 4095) * 256 + tid;
        const int rb = idx >> 15;
        const int r = idx & 32767;
        const int kt = r >> 11;
        const int h = (r >> 10) & 1;
        const int L = r & 1023;
        const int Lr = L >> 3;
        const int j = L & 7;
        const int c = j ^ (Lr & 7);
        int Rl;
        if (side == 0) Rl = (Lr & 63) + ((Lr & 64) << 1) + h * 64;
        else           Rl = ((Lr >> 5) << 6) + h * 32 + (Lr & 31);
        const float* sp = src + (size_t)(rb * 256 + Rl) * I_ + kt * 64 + c * 8;
        const float4 f0 = *(const float4*)(sp);
        const float4 f1 = *(const float4*)(sp + 4);
        const float f[8] = {f0.x, f0.y, f0.z, f0.w, f1.x, f1.y, f1.z, f1.w};
        ushort8 v;
        #pragma unroll
        for (int e = 0; e < 8; ++e)
            v[e] = __builtin_bit_cast(unsigned short, __float2bfloat16(f[e]));
        *(ushort8*)(dst + (size_t)idx * 8) = v;
        return;
    }

    // ---------------- argmin role ----------------
    const int aidx = bid / 3;                        // 0..4095
    const int w = tid >> 6, l = tid & 63;
    const int op0 = (aidx & 63) * 128;
    const int nw = (aidx >> 6) * 128 + w * 32;
    const int lr = l & 15, lk = l >> 4;

    f32x4 acc[8][2];
    #pragma unroll
    for (int of = 0; of < 8; ++of)
        #pragma unroll
        for (int nf = 0; nf < 2; ++nf) acc[of][nf] = (f32x4)(0.f);

    #pragma unroll
    for (int ks = 0; ks < 2; ++ks) {
        const int ko = ks * 32 + lk * 8;
        bf16x8 Ah[8], Al[8], Bh[2], Bl[2];
        #pragma unroll
        for (int of = 0; of < 8; ++of) {
            const size_t r = (size_t)(op0 + of * 16 + lr) * C_ + ko;
            Ah[of] = *(const bf16x8*)(ph + r);
            Al[of] = *(const bf16x8*)(pl + r);
        }
        #pragma unroll
        for (int nf = 0; nf < 2; ++nf) {
            const size_t r = (size_t)(nw + nf * 16 + lr) * C_ + ko;
            Bh[nf] = *(const bf16x8*)(ch + r);
            Bl[nf] = *(const bf16x8*)(cl + r);
        }
        #pragma unroll
        for (int of = 0; of < 8; ++of)
            #pragma unroll
            for (int nf = 0; nf < 2; ++nf) {
                acc[of][nf] = __builtin_amdgcn_mfma_f32_16x16x32_bf16(Ah[of], Bh[nf], acc[of][nf], 0, 0, 0);
                acc[of][nf] = __builtin_amdgcn_mfma_f32_16x16x32_bf16(Ah[of], Bl[nf], acc[of][nf], 0, 0, 0);
                acc[of][nf] = __builtin_amdgcn_mfma_f32_16x16x32_bf16(Al[of], Bh[nf], acc[of][nf], 0, 0, 0);
            }
    }

    #pragma unroll
    for (int of = 0; of < 8; ++of) {
        const int oprow0 = op0 + of * 16;
        const f32x4 ps = *(const f32x4*)(psq + oprow0 + lk * 4);
        #pragma unroll
        for (int nf = 0; nf < 2; ++nf) {
            const float d0 = fmaf(-2.f, acc[of][nf][0], ps[0]);
            const float d1 = fmaf(-2.f, acc[of][nf][1], ps[1]);
            const float d2 = fmaf(-2.f, acc[of][nf][2], ps[2]);
            const float d3 = fmaf(-2.f, acc[of][nf][3], ps[3]);
            const float e0 = __shfl_xor(d0, 16, 64);
            const float e1 = __shfl_xor(d1, 16, 64);
            const float e2 = __shfl_xor(d2, 16, 64);
            const float e3 = __shfl_xor(d3, 16, 64);
            float b1v = 3.4e38f, b2v = 3.4e38f;
            int bi = 0;
            #define UPD(val, pidx) do { const float _f = (val);                       \
                if (_f < b1v) { b2v = b1v; b1v = _f; bi = (pidx); }                   \
                else if (_f < b2v) b2v = _f; } while (0)
            UPD(d0, 0); UPD(d1, 1); UPD(d2, 2); UPD(d3, 3);
            UPD(e0, 4); UPD(e1, 5); UPD(e2, 6); UPD(e3, 7);
            #undef UPD
            if ((lk & 1) == 0) {
                const int o = (oprow0 >> 3) + (lk >> 1);
                const int n = nw + nf * 16 + lr;
                const unsigned flag = (b2v - b1v < 4e-3f) ? 0x80u : 0u;
                best[(size_t)o * N_ + n] = (unsigned char)((unsigned)bi | flag);
            }
        }
    }
}

// ---------------------------------------------------------------------------
// Kernel F: block-local fixup (merged compact+refine, NO global atomics).
// Each block scans its 8 KB slab of best into an LDS queue, then refines
// its flagged entries: 8 lanes/elem, fp64 exact, ascending-p first-min
// (identical semantics to the validated refine_wl). Clears flag bits.
// ---------------------------------------------------------------------------
__global__ __launch_bounds__(256)
void fixup_kernel(const float* __restrict__ ctx, const float* __restrict__ protos,
                  unsigned char* __restrict__ best) {
    __shared__ unsigned q[8192];
    __shared__ unsigned qcnt;
    const int tid = threadIdx.x;
    if (tid == 0) qcnt = 0;
    __syncthreads();

    const size_t base = (size_t)blockIdx.x * 8192;   // byte offset into best
    const uint4* bw4 = (const uint4*)(best + base);
    #pragma unroll
    for (int i = 0; i < 2; ++i) {
        const uint4 v = bw4[tid * 2 + i];
        const unsigned wds[4] = {v.x, v.y, v.z, v.w};
        #pragma unroll
        for (int wq = 0; wq < 4; ++wq) {
            unsigned fl = wds[wq] & 0x80808080u;
            while (fl) {
                const int bq = __builtin_ctz(fl) >> 3;   // flagged byte in word
                fl &= fl - 1;
                const unsigned slot = atomicAdd(&qcnt, 1u);
                q[slot] = (unsigned)(tid * 32 + i * 16 + wq * 4 + bq);
            }
        }
    }
    __syncthreads();

    const unsigned cnt = qcnt;
    const int lane8 = tid & 7;
    for (unsigned e = (unsigned)(tid >> 3); e < cnt; e += 32) {
        const size_t off = base + q[e];
        const int n = (int)(off & (N_ - 1));
        const int o = (int)(off >> 13);
        const float* cr = ctx + (size_t)n * C_;
        const float* pr = protos + ((size_t)o * 8 + lane8) * C_;
        double s = 0.0;
        #pragma unroll 8
        for (int c = 0; c < C_; ++c) {
            const double pv = (double)pr[c];
            const double cv = (double)cr[c];
            s += pv * (pv - 2.0 * cv);
        }
        int bi = lane8;
        #pragma unroll
        for (int d = 1; d < 8; d <<= 1) {
            const double s2 = __shfl_xor(s, d, 64);
            const int b2 = __shfl_xor(bi, d, 64);
            if (s2 < s || (s2 == s && b2 < bi)) { s = s2; bi = b2; }
        }
        if (lane8 == 0) best[off] = (unsigned char)bi;
    }
}

// ---------------------------------------------------------------------------
// Kernel B: 256x256 phase-pipelined bf16 MFMA GEMM — r10 schedule, with the
// explicit lgkmcnt(0) full-drains REMOVED (ds_reads are compiler-visible
// loads; the waitcnt pass inserts fine-grained lgkmcnt before each MFMA,
// letting early MFMAs overlap late ds_reads). Cross-wave race margin is
// identical to r10 (LGKM0 never delayed the staging wave).
// ---------------------------------------------------------------------------
__global__ __launch_bounds__(512, 1)
void gemm_gather_kernel(const unsigned short* __restrict__ Xb,
                        const unsigned short* __restrict__ Wb,
                        const float* __restrict__ bias,
                        const unsigned char* __restrict__ best,
                        float* __restrict__ out) {
    extern __shared__ unsigned short lds[];  // 2 x (A 16384 + B 16384) ushort = 128 KiB

    int wg = blockIdx.x;                     // 1024 blocks, %8==0 -> bijective
    wg = (wg & 7) * 128 + (wg >> 3);
    const int bx = wg & 31;
    const int by = wg >> 5;
    const int n0 = by * 256;
    const int col0 = bx * 256;

    const int tid = threadIdx.x;
    const int w = tid >> 6, l = tid & 63;
    const int wr = w >> 2, wc = w & 3;
    const int lr = l & 15, lk = l >> 4;
    const int lx = lr & 7;

    const unsigned short* Xrb = Xb + (size_t)(n0 >> 8) * 262144;
    const unsigned short* Wrb = Wb + (size_t)(col0 >> 8) * 262144;

    #define STAGE(src, ktt, h, ldsofs) do {                                          \
        const unsigned short* _g = (src) + ((size_t)(ktt) * 2 + (h)) * 8192;         \
        __builtin_amdgcn_global_load_lds(GLOBAL_AS(_g + (size_t)tid * 8),            \
            LDS_AS(lds + (ldsofs) + tid * 8), 16, 0, 0);                             \
        __builtin_amdgcn_global_load_lds(GLOBAL_AS(_g + (size_t)(tid + 512) * 8),    \
            LDS_AS(lds + (ldsofs) + (tid + 512) * 8), 16, 0, 0);                     \
    } while (0)

    #define VMCNT4() do { asm volatile("s_waitcnt vmcnt(4)" ::: "memory");           \
        __builtin_amdgcn_sched_barrier(0); } while (0)
    #define VMCNT2() do { asm volatile("s_waitcnt vmcnt(2)" ::: "memory");           \
        __builtin_amdgcn_sched_barrier(0); } while (0)
    #define VMCNT0() do { asm volatile("s_waitcnt vmcnt(0)" ::: "memory");           \
        __builtin_amdgcn_sched_barrier(0); } while (0)
    #define BAR() __builtin_amdgcn_s_barrier()

    f32x4 acc[8][4];
    #pragma unroll
    for (int m = 0; m < 8; ++m)
        #pragma unroll
        for (int n = 0; n < 4; ++n) acc[m][n] = (f32x4)(0.f);

    #define RD_A(dst, mbase, bb) do {                                                \
        _Pragma("unroll")                                                            \
        for (int _m = 0; _m < 4; ++_m) {                                             \
            const int _R = wr * 128 + ((mbase) + _m) * 16 + lr;                      \
            const int _h = (_R >> 6) & 1;                                            \
            const int _Lr = (_R & 63) + ((_R & 128) >> 1);                           \
            _Pragma("unroll")                                                        \
            for (int _k = 0; _k < 2; ++_k) {                                         \
                const int _s = (_k * 4 + lk) ^ lx;                                   \
                dst[_m][_k] = *(const bf16x8*)&lds[(bb) * 32768 + _h * 8192 +        \
                                                   _Lr * 64 + _s * 8];               \
            }                                                                        \
        }                                                                            \
    } while (0)

    #define RD_B(dst, nbase, bb) do {                                                \
        _Pragma("unroll")                                                            \
        for (int _n = 0; _n < 2; ++_n) {                                             \
            const int _R = wc * 64 + ((nbase) + _n) * 16 + lr;                       \
            const int _h = (_R >> 5) & 1;                                            \
            const int _Lr = ((_R >> 6) << 5) + (_R & 31);                            \
            _Pragma("unroll")                                                        \
            for (int _k = 0; _k < 2; ++_k) {                                         \
                const int _s = (_k * 4 + lk) ^ lx;                                   \
                dst[_n][_k] = *(const bf16x8*)&lds[(bb) * 32768 + 16384 +            \
                                                   _h * 8192 + _Lr * 64 + _s * 8];   \
            }                                                                        \
        }                                                                            \
    } while (0)

    #define MFMA16(AF, BF, MB, NB) do {                                              \
        __builtin_amdgcn_s_setprio(1);                                               \
        _Pragma("unroll")                                                            \
        for (int _m = 0; _m < 4; ++_m)                                               \
            _Pragma("unroll")                                                        \
            for (int _n = 0; _n < 2; ++_n)                                           \
                _Pragma("unroll")                                                    \
                for (int _k = 0; _k < 2; ++_k)                                       \
                    acc[(MB) + _m][(NB) + _n] =                                      \
                        __builtin_amdgcn_mfma_f32_16x16x32_bf16(                     \
                            AF[_m][_k], BF[_n][_k], acc[(MB) + _m][(NB) + _n], 0, 0, 0); \
        __builtin_amdgcn_s_setprio(0);                                               \
    } while (0)

    bf16x8 af[4][2], bfa[2][2], bfb[2][2];

    // ---- prologue: stage kt0 {Aa,Ba,Bb,Ab}; drain Aa0,Ba0 ----
    STAGE(Xrb, 0, 0, 0);
    STAGE(Wrb, 0, 0, 16384);
    STAGE(Wrb, 0, 1, 16384 + 8192);
    STAGE(Xrb, 0, 1, 8192);
    VMCNT4();
    BAR();

    #pragma unroll 1
    for (int kt = 0; kt < 15; ++kt) {
        const int b = kt & 1, nb = b ^ 1;
        const int nbo = nb * 32768;
        RD_A(af, 0, b);
        RD_B(bfa, 0, b);
        STAGE(Wrb, kt + 1, 0, nbo + 16384);
        VMCNT4();
        BAR();
        MFMA16(af, bfa, 0, 0);
        RD_B(bfb, 2, b);
        STAGE(Xrb, kt + 1, 0, nbo);
        VMCNT4();
        BAR();
        MFMA16(af, bfb, 0, 2);
        RD_A(af, 4, b);
        STAGE(Wrb, kt + 1, 1, nbo + 16384 + 8192);
        VMCNT4();
        BAR();
        MFMA16(af, bfb, 4, 2);
        RD_B(bfa, 0, b);
        STAGE(Xrb, kt + 1, 1, nbo + 8192);
        VMCNT4();
        BAR();
        MFMA16(af, bfa, 4, 0);
    }
    {   // tail kt=15 (buf 1, no staging)
        RD_A(af, 0, 1);
        RD_B(bfa, 0, 1);
        VMCNT2();
        BAR();
        MFMA16(af, bfa, 0, 0);
        RD_B(bfb, 2, 1);
        VMCNT0();
        BAR();
        MFMA16(af, bfb, 0, 2);
        RD_A(af, 4, 1);
        MFMA16(af, bfb, 4, 2);
        RD_B(bfa, 0, 1);
        MFMA16(af, bfa, 4, 0);
    }

    // ---- epilogue: fused argmin-gather + bias; u32 best loads ----
    const int nbase = n0 + wr * 128 + lk * 4;
    #pragma unroll
    for (int nf = 0; nf < 4; ++nf) {
        const int opcol = col0 + wc * 64 + nf * 16 + lr;
        const int o = opcol >> 3;
        const unsigned p = (unsigned)(opcol & 7);
        const float bv = bias[opcol];
        const unsigned char* brow = best + (size_t)o * N_ + nbase;
        #pragma unroll
        for (int m = 0; m < 8; ++m) {
            const unsigned b4 = *(const unsigned*)(brow + m * 16);
            #pragma unroll
            for (int j = 0; j < 4; ++j) {
                if (((b4 >> (j * 8)) & 255u) == p) {
                    const int n = nbase + m * 16 + j;
                    out[(size_t)n * O_ + o] = acc[m][nf][j] + bv;
                }
            }
        }
    }
    #undef STAGE
    #undef RD_A
    #undef RD_B
    #undef MFMA16
    #undef VMCNT4
    #undef VMCNT2
    #undef VMCNT0
    #undef BAR
}

// ---------------------------------------------------------------------------
extern "C" void kernel_launch(void* const* d_in, const int* in_sizes, int n_in,
                              void* d_out, int out_size, void* d_ws, size_t ws_size,
                              hipStream_t stream) {
    const float* X      = (const float*)d_in[0];
    const float* ctx    = (const float*)d_in[1];
    const float* W      = (const float*)d_in[2];
    const float* bias   = (const float*)d_in[3];
    const float* protos = (const float*)d_in[4];
    float* out = (float*)d_out;

    char* ws = (char*)d_ws;
    unsigned char* best = (unsigned char*)ws;                         // 8 MiB
    float* psq = (float*)(ws + ((size_t)8 << 20));                    // 32 KiB
    unsigned short* Xb = (unsigned short*)(ws + ((size_t)9 << 20));   // 16 MiB
    unsigned short* Wb = (unsigned short*)(ws + ((size_t)25 << 20));  // 16 MiB

    // split-bf16 scratch lives in d_out (fully overwritten by gemm later)
    char* ob = (char*)d_out;
    unsigned short* ph = (unsigned short*)(ob + ((size_t)16 << 20));  // 1 MiB
    unsigned short* pl = (unsigned short*)(ob + ((size_t)17 << 20));  // 1 MiB
    unsigned short* ch = (unsigned short*)(ob + ((size_t)18 << 20));  // 1 MiB
    unsigned short* cl = (unsigned short*)(ob + ((size_t)19 << 20));  // 1 MiB

    hipFuncSetAttribute((const void*)gemm_gather_kernel,
                        hipFuncAttributeMaxDynamicSharedMemorySize, 131072);

    prep_kernel<<<dim3(544), dim3(256), 0, stream>>>(protos, ctx, ph, pl, ch, cl, psq);
    mega_kernel<<<dim3(12288), dim3(256), 0, stream>>>(X, W, Xb, Wb, ph, pl, ch, cl, psq, best);
    fixup_kernel<<<dim3(1024), dim3(256), 0, stream>>>(ctx, protos, best);
    gemm_gather_kernel<<<dim3(1024), dim3(512), 131072, stream>>>(Xb, Wb, bias, best, out);
}